// Round 9
// baseline (258.578 us; speedup 1.0000x reference)
//
#include <hip/hip_runtime.h>
#include <hip/hip_cooperative_groups.h>

namespace cg = cooperative_groups;

#define B_ 8
#define L_ 2048
#define D_ 256
#define BK 32
#define KSPLIT 2
#define KQ (L_/KSPLIT)         // 1024 keys per split
#define NIT (KQ/BK)            // 32 iterations
#define PSTR 40
#define NROW (B_*L_)           // 16384
#define NE ((size_t)B_*L_*D_)  // 4194304
#define THR 13.0f              // defer-max threshold, log2 domain (~e^9), fp16-safe
#define MINIT (-1e30f)
#define LOG2E_F 1.44269504f

typedef __attribute__((ext_vector_type(8))) _Float16 f16x8;
typedef __attribute__((ext_vector_type(4))) _Float16 hf4;
typedef __attribute__((ext_vector_type(4))) float f32x4;

#define MFMA16F(a,b,c) __builtin_amdgcn_mfma_f32_16x16x32_f16((a),(b),(c),0,0,0)
#define NEG_INF (-__builtin_inff())
#define GLL(src,dst) __builtin_amdgcn_global_load_lds( \
    (const __attribute__((address_space(1))) void*)(src), \
    (__attribute__((address_space(3))) void*)(dst), 16, 0, 0)

__device__ __forceinline__ f32x4 fmax4(f32x4 a, f32x4 b){
  f32x4 r;
  r[0]=fmaxf(a[0],b[0]); r[1]=fmaxf(a[1],b[1]);
  r[2]=fmaxf(a[2],b[2]); r[3]=fmaxf(a[3],b[3]);
  return r;
}

// ---- prep core: one 32-key tile -> x16 rows + vtl tile (r8 layout) ----
__device__ __forceinline__ void prep_core(const float* __restrict__ x,
                                          _Float16* __restrict__ x16,
                                          _Float16* __restrict__ vtl,
                                          int tIdx, int bb, int t, char* smem){
  _Float16 (*T)[258] = (_Float16(*)[258])smem;   // 32*258*2 = 16.5 KB
  const int l0 = tIdx*32;
  #pragma unroll
  for (int i=0;i<4;++i){
    const int n8 = t + 256*i;
    const int row = n8>>5;
    const int c   = (n8&31)*8;
    size_t idx = ((size_t)(bb*L_ + l0 + row))*D_ + c;
    float4 v0 = *(const float4*)(x + idx);
    float4 v1 = *(const float4*)(x + idx + 4);
    f16x8 h;
    h[0]=(_Float16)v0.x; h[1]=(_Float16)v0.y; h[2]=(_Float16)v0.z; h[3]=(_Float16)v0.w;
    h[4]=(_Float16)v1.x; h[5]=(_Float16)v1.y; h[6]=(_Float16)v1.z; h[7]=(_Float16)v1.w;
    *(f16x8*)(x16 + idx) = h;
    *(f16x8*)(&T[row][c]) = h;
  }
  __syncthreads();
  _Float16* vb = vtl + ((size_t)(bb*64 + tIdx))*8192;
  #pragma unroll
  for (int i=0;i<4;++i){
    const int q = t + 256*i;
    const int d = q>>2, ph = q&3;
    const int kc = ph ^ ((d>>1)&3);
    const int k0 = kc*8;
    f16x8 h;
    #pragma unroll
    for (int j=0;j<8;++j) h[j] = T[k0+j][d];
    *(f16x8*)(vb + (size_t)q*8) = h;
  }
}

// ---- flash core: r8's proven QBLK=16 one-tile P/V pipeline, exp2 domain ----
__device__ __forceinline__ void flash_core(const _Float16* __restrict__ x16,
                                           const _Float16* __restrict__ vtl,
                                           const int* __restrict__ mask,
                                           char* smem, int b, int z, int qblk,
                                           int wave, int lane,
                                           f32x4 (&O)[16], f32x4& Osum, f32x4& M){
  _Float16 (*sK)[8192] = (_Float16(*)[8192])smem;            // 32 KB
  _Float16 (*sV)[8192] = (_Float16(*)[8192])(smem + 32768);  // 32 KB
  typedef _Float16 sPhalf[4][16*PSTR];
  sPhalf* sP = (sPhalf*)(smem + 65536);                      // 10 KB

  const int quad = lane >> 4, l16 = lane & 15;
  const int q0w = qblk*64 + wave*16;
  const int sw = l16 & 7, vsw = (l16>>1)&3;

  f16x8 qh[8];
  {
    const _Float16* qr = x16 + ((size_t)(b*L_ + q0w + l16))*D_;
    const _Float16 l2e = (_Float16)LOG2E_F;
    #pragma unroll
    for (int ks=0; ks<8; ++ks){
      f16x8 h = *(const f16x8*)(qr + ks*32 + quad*8);
      #pragma unroll
      for (int j=0;j<8;++j) h[j] = h[j] * l2e;   // log2-domain scores
      qh[ks] = h;
    }
  }
  unsigned long long mb = 0;
  {
    const int* mrow = mask + b*L_ + z*KQ;
    #pragma unroll
    for (int j=0;j<64;++j)
      mb |= (unsigned long long)(mrow[j*16 + l16] ? 1u : 0u) << j;
  }

  M = (f32x4){MINIT, MINIT, MINIT, MINIT};

  unsigned kof[4], vof[4], dof[4];
  #pragma unroll
  for (int i=0;i<4;++i){
    int c = (wave + i*4)*64 + lane;
    int r = c>>5, pk = c&31;
    kof[i] = (unsigned)(r*512 + ((pk ^ (r&7))*16));
    vof[i] = (unsigned)(c*16);
    dof[i] = (unsigned)((wave + i*4)*1024);
  }
  const char* kbase = (const char*)x16 + ((size_t)b*L_ + (size_t)z*KQ)*(D_*2);
  const char* vbase = (const char*)vtl + ((size_t)(b*64 + z*32))*16384;

  #pragma unroll
  for (int i=0;i<4;++i) GLL(kbase + kof[i], (char*)sK[0] + dof[i]);

  #pragma unroll
  for (int i=0;i<16;i++) O[i] = (f32x4){0.f,0.f,0.f,0.f};
  Osum = (f32x4){0.f,0.f,0.f,0.f};
  f16x8 ones;
  #pragma unroll
  for (int j=0;j<8;++j) ones[j] = (_Float16)1.0f;

  __syncthreads();   // K_0 visible

  for (int it=0; it<NIT; ++it){
    if (it+1 < NIT){
      const char* kb2 = kbase + (size_t)(it+1)*16384;
      char* kd = (char*)sK[(it+1)&1];
      #pragma unroll
      for (int i=0;i<4;++i) GLL(kb2 + kof[i], kd + dof[i]);
    }
    {
      const char* vb2 = vbase + (size_t)it*16384;
      char* vd = (char*)sV[it&1];
      #pragma unroll
      for (int i=0;i<4;++i) GLL(vb2 + vof[i], vd + dof[i]);
    }
    const _Float16* kb = sK[it&1];

    // ---- S = Q·K^T (tile t, log2 domain) ----
    f32x4 S[2];
    S[0]=(f32x4){0,0,0,0}; S[1]=(f32x4){0,0,0,0};
    #pragma unroll
    for (int ks=0; ks<8; ++ks){
      f16x8 b0 = *(const f16x8*)(kb + (     l16)*256 + (((ks*4+quad)^sw)*8));
      f16x8 b1 = *(const f16x8*)(kb + (16 + l16)*256 + (((ks*4+quad)^sw)*8));
      S[0] = MFMA16F(qh[ks], b0, S[0]);
      S[1] = MFMA16F(qh[ks], b1, S[1]);
    }

    // ---- PV (tile t-1) ----
    if (it > 0){
      const _Float16* vb = sV[(it-1)&1];
      f16x8 pf = *(const f16x8*)(&sP[(it-1)&1][wave][l16*PSTR + quad*8]);
      #pragma unroll
      for (int vt=0; vt<16; ++vt){
        f16x8 bv = *(const f16x8*)(vb + (vt*16+l16)*32 + ((quad^vsw)*8));
        O[vt] = MFMA16F(pf, bv, O[vt]);
      }
      Osum = MFMA16F(pf, ones, Osum);
    }

    // ---- diag zero, then key padding mask ----
    {
      const int d0 = q0w - (z*KQ + it*BK);
      if ((unsigned)d0 < 32u){
        const int ntd = d0 >> 4;
        #pragma unroll
        for (int r=0;r<4;++r)
          S[ntd][r] = (l16 == quad*4+r) ? 0.0f : S[ntd][r];
      }
    }
    {
      const unsigned mw = (unsigned)(mb >> (unsigned)(it*2));
      const float mk0 = (mw & 1u) ? NEG_INF : 0.0f;
      const float mk1 = (mw & 2u) ? NEG_INF : 0.0f;
      #pragma unroll
      for (int r=0;r<4;++r){ S[0][r] += mk0; S[1][r] += mk1; }
    }

    // ---- defer-max check ----
    {
      f32x4 t = fmax4(S[0], S[1]);
      int ok = 1;
      #pragma unroll
      for (int r=0;r<4;++r) ok &= (t[r] <= M[r] + THR);
      if (!__all(ok)){
        #pragma unroll
        for (int off=1; off<16; off<<=1){
          f32x4 o;
          o[0]=__shfl_xor(t[0],off); o[1]=__shfl_xor(t[1],off);
          o[2]=__shfl_xor(t[2],off); o[3]=__shfl_xor(t[3],off);
          t = fmax4(t,o);
        }
        f32x4 mn = fmax4(M, t);
        float sc[4];
        #pragma unroll
        for (int r=0;r<4;++r) sc[r] = exp2f(M[r] - mn[r]);
        #pragma unroll
        for (int vt=0; vt<16; ++vt){
          #pragma unroll
          for (int r=0;r<4;++r) O[vt][r] *= sc[r];
        }
        #pragma unroll
        for (int r=0;r<4;++r) Osum[r] *= sc[r];
        M = mn;
      }
    }

    // ---- P = 2^(S - M) -> sP[t&1] ----
    #pragma unroll
    for (int r=0;r<4;++r){
      const int row = quad*4 + r;
      sP[it&1][wave][row*PSTR +      l16] = (_Float16)exp2f(S[0][r] - M[r]);
      sP[it&1][wave][row*PSTR + 16 + l16] = (_Float16)exp2f(S[1][r] - M[r]);
    }

    __syncthreads();
  }

  // ---- drain: PV for the last tile ----
  {
    const _Float16* vb = sV[(NIT-1)&1];
    f16x8 pf = *(const f16x8*)(&sP[(NIT-1)&1][wave][l16*PSTR + quad*8]);
    #pragma unroll
    for (int vt=0; vt<16; ++vt){
      f16x8 bv = *(const f16x8*)(vb + (vt*16+l16)*32 + ((quad^vsw)*8));
      O[vt] = MFMA16F(pf, bv, O[vt]);
    }
    Osum = MFMA16F(pf, ones, Osum);
  }
}

// ---- fused cooperative kernel: prep | sync | flash | sync | combine ----
// 512 blocks x 256 threads, 2 blocks/CU co-resident (LDS 74KB, VGPR ~128).
// z=1 blocks publish fp16 fragment partials + (m,l); z=0 blocks combine
// against their in-register O and write `out` directly — no combine kernel,
// half the oall traffic, no dispatch boundaries.
__launch_bounds__(256, 2)
__global__ void fused_k(const float* __restrict__ x,
                        const int* __restrict__ mask,
                        float* __restrict__ out,
                        _Float16* __restrict__ x16,
                        _Float16* __restrict__ vtl,
                        _Float16* __restrict__ oall,
                        float* __restrict__ mll,
                        float* __restrict__ mm){
  __shared__ __attribute__((aligned(16))) char smem[75776];   // 74 KB
  const int tid = threadIdx.x;
  const int bid = blockIdx.x;
  const int wave = tid >> 6, lane = tid & 63;
  const int quad = lane >> 4, l16 = lane & 15;

  // ---- phase 1: prep (bid -> tile 0..63, batch 0..7) ----
  prep_core(x, x16, vtl, bid & 63, bid >> 6, tid, smem);
  cg::this_grid().sync();

  // ---- phase 2: flash (bid -> z, b, qblk) ----
  const int z = bid >> 8, b = (bid >> 5) & 7, qblk = bid & 31;
  f32x4 O[16], Osum, M;
  flash_core(x16, vtl, mask, smem, b, z, qblk, wave, lane, O, Osum, M);

  const int u = b*(L_/16) + qblk*4 + wave;

  // ---- phase 3a: z=1 publishes partials ----
  if (z == 1){
    _Float16* ob = oall + (size_t)u*4096;
    #pragma unroll
    for (int vt=0; vt<16; ++vt){
      hf4 hh;
      #pragma unroll
      for (int r=0;r<4;++r) hh[r] = (_Float16)O[vt][r];
      *(hf4*)(ob + vt*256 + lane*4) = hh;
    }
    if (l16 == 0){
      const int row = u*16 + quad*4;
      #pragma unroll
      for (int r=0;r<4;++r){
        mll[row + r] = Osum[r];
        mm [row + r] = M[r];          // log2 domain
      }
    }
  }
  cg::this_grid().sync();
  if (z == 1) return;

  // ---- phase 3b: z=0 combines in-register O with z=1's partial ----
  const int row0 = u*16 + quad*4;
  f32x4 mz1 = *(const f32x4*)(mm  + row0);
  f32x4 lz1 = *(const f32x4*)(mll + row0);
  f32x4 ms = fmax4(M, mz1);
  float s0[4], s1[4], inv[4];
  #pragma unroll
  for (int r=0;r<4;++r){
    s0[r] = exp2f(M[r]   - ms[r]);
    s1[r] = exp2f(mz1[r] - ms[r]);
    inv[r] = 1.0f/(s0[r]*Osum[r] + s1[r]*lz1[r]);
  }

  float* t2 = (float*)smem + wave*4160;   // per-wave 16x260 f32 (16.6 KB)
  #pragma unroll
  for (int vt=0; vt<16; ++vt){
    hf4 v1 = *(const hf4*)(oall + (size_t)u*4096 + vt*256 + lane*4);
    #pragma unroll
    for (int r=0;r<4;++r)
      t2[(quad*4+r)*260 + vt*16 + l16] =
        (s0[r]*O[vt][r] + s1[r]*(float)v1[r]) * inv[r];
  }
  __syncthreads();
  #pragma unroll
  for (int p=0;p<16;++p){
    float4 vv = *(const float4*)(t2 + p*260 + lane*4);
    *(float4*)(out + ((size_t)(u*16 + p))*D_ + lane*4) = vv;
  }
}

// ================= fallback path (non-cooperative, r8 structure) ==========
__global__ void prep_fb(const float* __restrict__ x,
                        _Float16* __restrict__ x16,
                        _Float16* __restrict__ vtl){
  __shared__ __attribute__((aligned(16))) char smem[16512];
  prep_core(x, x16, vtl, blockIdx.x, blockIdx.y, threadIdx.x, smem);
}

__launch_bounds__(256, 2)
__global__ void flash_fb(const _Float16* __restrict__ x16,
                         const _Float16* __restrict__ vtl,
                         const int* __restrict__ mask,
                         _Float16* __restrict__ oall,
                         float* __restrict__ mll,
                         float* __restrict__ mm){
  __shared__ __attribute__((aligned(16))) char smem[75776];
  const int tid = threadIdx.x;
  const int wave = tid >> 6, lane = tid & 63;
  const int quad = lane >> 4, l16 = lane & 15;
  const int b = blockIdx.y, z = blockIdx.z;
  f32x4 O[16], Osum, M;
  flash_core(x16, vtl, mask, smem, b, z, blockIdx.x, wave, lane, O, Osum, M);
  const int u = b*(L_/16) + blockIdx.x*4 + wave;
  _Float16* ob = oall + (size_t)z*NE + (size_t)u*4096;
  #pragma unroll
  for (int vt=0; vt<16; ++vt){
    hf4 hh;
    #pragma unroll
    for (int r=0;r<4;++r) hh[r] = (_Float16)O[vt][r];
    *(hf4*)(ob + vt*256 + lane*4) = hh;
  }
  if (l16 == 0){
    const int row = u*16 + quad*4;
    #pragma unroll
    for (int r=0;r<4;++r){
      mll[z*NROW + row + r] = Osum[r];
      mm [z*NROW + row + r] = M[r];
    }
  }
}

__global__ void combine_fb(float* __restrict__ out,
                           const _Float16* __restrict__ oall,
                           const float* __restrict__ mll,
                           const float* __restrict__ mm){
  __shared__ float T2[16][260];
  const int t = threadIdx.x, u = blockIdx.x;
  const int quad = (t>>4)&3, l16 = t&15;
  const int row0 = u*16 + quad*4;

  f32x4 mz[KSPLIT], lz[KSPLIT];
  #pragma unroll
  for (int zc=0; zc<KSPLIT; ++zc){
    mz[zc] = *(const f32x4*)(mm  + zc*NROW + row0);
    lz[zc] = *(const f32x4*)(mll + zc*NROW + row0);
  }
  f32x4 ms = fmax4(mz[0], mz[1]);
  float sc[KSPLIT][4];
  f32x4 den = (f32x4){0.f,0.f,0.f,0.f};
  #pragma unroll
  for (int zc=0; zc<KSPLIT; ++zc){
    #pragma unroll
    for (int r=0;r<4;++r){
      sc[zc][r] = exp2f(mz[zc][r] - ms[r]);
      den[r] += sc[zc][r] * lz[zc][r];
    }
  }
  float inv[4];
  #pragma unroll
  for (int r=0;r<4;++r) inv[r] = 1.0f/den[r];

  #pragma unroll
  for (int i=0;i<4;++i){
    const int f = t + 256*i;
    const int vt = f>>6;
    float acc[4] = {0.f,0.f,0.f,0.f};
    #pragma unroll
    for (int zc=0; zc<KSPLIT; ++zc){
      hf4 v = *(const hf4*)(oall + (size_t)zc*NE + (size_t)u*4096 + (size_t)f*4);
      #pragma unroll
      for (int r=0;r<4;++r) acc[r] += sc[zc][r] * (float)v[r];
    }
    #pragma unroll
    for (int r=0;r<4;++r) T2[quad*4+r][vt*16+l16] = acc[r]*inv[r];
  }
  __syncthreads();
  #pragma unroll
  for (int p=0;p<4;++p){
    const int row = (t>>6) + p*4, col = (t&63)*4;
    float4 vv = *(const float4*)&T2[row][col];
    *(float4*)(out + ((size_t)u*16 + row)*D_ + col) = vv;
  }
}

extern "C" void kernel_launch(void* const* d_in, const int* in_sizes, int n_in,
                              void* d_out, int out_size, void* d_ws, size_t ws_size,
                              hipStream_t stream) {
  const float* x    = (const float*)d_in[0];
  const int*   mask = (const int*)d_in[1];
  float*       out  = (float*)d_out;

  _Float16* x16  = (_Float16*)d_ws;
  _Float16* vtl  = x16 + NE;
  _Float16* oall = vtl + NE;                         // up to KSPLIT*NE fp16
  float*    mll  = (float*)(oall + (size_t)KSPLIT*NE);
  float*    mm   = mll + (size_t)KSPLIT*NROW;

  void* args[] = {(void*)&x, (void*)&mask, (void*)&out,
                  (void*)&x16, (void*)&vtl, (void*)&oall,
                  (void*)&mll, (void*)&mm};
  hipError_t e = hipLaunchCooperativeKernel((const void*)fused_k,
                                            dim3(512), dim3(256),
                                            args, 0, stream);
  if (e != hipSuccess){
    prep_fb   <<<dim3(L_/32, B_),        dim3(256), 0, stream>>>(x, x16, vtl);
    flash_fb  <<<dim3(L_/64, B_, KSPLIT),dim3(256), 0, stream>>>(x16, vtl, mask, oall, mll, mm);
    combine_fb<<<dim3(NROW/16),          dim3(256), 0, stream>>>(out, oall, mll, mm);
  }
}